// Round 2
// baseline (824.890 us; speedup 1.0000x reference)
//
#include <hip/hip_runtime.h>

#define T_TOK 8192
#define DDIM 1024
#define HDIM 2048
#define NEXP 8

typedef __attribute__((ext_vector_type(8))) short short8;
typedef __attribute__((ext_vector_type(4))) float f32x4;

__device__ __forceinline__ unsigned short f2bf(float f) {
  unsigned int u = __builtin_bit_cast(unsigned int, f);
  u += 0x7fffu + ((u >> 16) & 1u);   // RNE
  return (unsigned short)(u >> 16);
}
__device__ __forceinline__ float bf2f(unsigned short h) {
  unsigned int u = ((unsigned int)h) << 16;
  return __builtin_bit_cast(float, u);
}
__device__ __forceinline__ void gload16(const void* g, void* l) {
  __builtin_amdgcn_global_load_lds((const __attribute__((address_space(1))) void*)g,
                                   (__attribute__((address_space(3))) void*)l, 16, 0, 0);
}
__device__ __forceinline__ int imin(int a, int b) { return a < b ? a : b; }

// ---------------- fp32 -> bf16 straight convert (x) ----------------
__global__ __launch_bounds__(256) void cvt_kernel(const float* __restrict__ in,
                                                  unsigned short* __restrict__ out, int n) {
  int i = (blockIdx.x * 256 + threadIdx.x) * 8;
  int stride = gridDim.x * 256 * 8;
  for (; i < n; i += stride) {
    float4 a = *(const float4*)(in + i);
    float4 b = *(const float4*)(in + i + 4);
    alignas(16) unsigned short t[8] = {f2bf(a.x), f2bf(a.y), f2bf(a.z), f2bf(a.w),
                                       f2bf(b.x), f2bf(b.y), f2bf(b.z), f2bf(b.w)};
    *(uint4*)(out + i) = *(const uint4*)t;
  }
}

// ------------- fp32 [E][R][C] -> bf16 [E][C][R] transpose-convert -------------
__global__ __launch_bounds__(256) void tcvt_kernel(const float* __restrict__ in,
                                                   unsigned short* __restrict__ out,
                                                   int R, int C) {
  int e = blockIdx.z;
  int rb = blockIdx.y * 64, cb = blockIdx.x * 64;
  const float* inE = in + (size_t)e * R * C;
  unsigned short* outE = out + (size_t)e * R * C;
  __shared__ float tile[64][65];
  int tid = threadIdx.x;
  #pragma unroll
  for (int i = 0; i < 4; ++i) {
    int f = tid + i * 256;
    int r = f >> 4, c4 = (f & 15) << 2;
    float4 v = *(const float4*)(inE + (size_t)(rb + r) * C + cb + c4);
    tile[r][c4] = v.x; tile[r][c4 + 1] = v.y; tile[r][c4 + 2] = v.z; tile[r][c4 + 3] = v.w;
  }
  __syncthreads();
  #pragma unroll
  for (int i = 0; i < 2; ++i) {
    int g = tid + i * 256;
    int oc = g >> 3;          // original col = out row (0..63)
    int r8 = (g & 7) << 3;    // original row block (0..56)
    alignas(16) unsigned short tmp[8];
    #pragma unroll
    for (int j = 0; j < 8; ++j) tmp[j] = f2bf(tile[r8 + j][oc]);
    *(uint4*)(outE + (size_t)(cb + oc) * R + rb + r8) = *(const uint4*)tmp;
  }
}

// ---------------- gating: logits, softmax, top-2, counts ----------------
__global__ __launch_bounds__(256) void gate_kernel(const float* __restrict__ x,
                                                   const float* __restrict__ gw,
                                                   int* __restrict__ t_exp,
                                                   float* __restrict__ t_w,
                                                   int* __restrict__ counts) {
  int t = blockIdx.x * 4 + (threadIdx.x >> 6);
  int lane = threadIdx.x & 63;
  const float* xp = x + (size_t)t * DDIM;
  float acc[NEXP];
  #pragma unroll
  for (int e = 0; e < NEXP; ++e) acc[e] = 0.f;
  for (int i = 0; i < DDIM / 64; ++i) {
    int d = i * 64 + lane;
    float xv = xp[d];
    const float* g = gw + d * NEXP;
    #pragma unroll
    for (int e = 0; e < NEXP; ++e) acc[e] += xv * g[e];
  }
  #pragma unroll
  for (int off = 32; off > 0; off >>= 1) {
    #pragma unroll
    for (int e = 0; e < NEXP; ++e) acc[e] += __shfl_xor(acc[e], off, 64);
  }
  float mx = acc[0];
  #pragma unroll
  for (int e = 1; e < NEXP; ++e) mx = fmaxf(mx, acc[e]);
  float p[NEXP]; float S = 0.f;
  #pragma unroll
  for (int e = 0; e < NEXP; ++e) { p[e] = expf(acc[e] - mx); S += p[e]; }
  int i0 = 0; float v0 = p[0];
  #pragma unroll
  for (int e = 1; e < NEXP; ++e) if (p[e] > v0) { v0 = p[e]; i0 = e; }
  int i1 = -1; float v1 = -1.f;
  #pragma unroll
  for (int e = 0; e < NEXP; ++e) if (e != i0 && p[e] > v1) { v1 = p[e]; i1 = e; }
  float pv0 = v0 / S, pv1 = v1 / S;
  float denom = pv0 + pv1 + 1e-9f;
  if (lane == 0) {
    t_exp[t * 2] = i0; t_exp[t * 2 + 1] = i1;
    t_w[t * 2] = pv0 / denom; t_w[t * 2 + 1] = pv1 / denom;
    atomicAdd(&counts[i0], 1); atomicAdd(&counts[i1], 1);
  }
}

// ctrl layout: [0..8) counts, [8..16) offsets, [16..24) cursors
__global__ void offsets_kernel(int* ctrl) {
  if (threadIdx.x == 0 && blockIdx.x == 0) {
    int o = 0;
    for (int e = 0; e < NEXP; ++e) { ctrl[8 + e] = o; ctrl[16 + e] = o; o += ctrl[e]; }
  }
}

__global__ __launch_bounds__(256) void scatter_kernel(const int* __restrict__ t_exp,
                                                      const float* __restrict__ t_w,
                                                      int* __restrict__ ctrl,
                                                      int* __restrict__ row_tok,
                                                      float* __restrict__ row_w,
                                                      int* __restrict__ inv_row) {
  int t = blockIdx.x * 256 + threadIdx.x;
  if (t >= T_TOK) return;
  for (int s = 0; s < 2; ++s) {
    int e = t_exp[t * 2 + s];
    int pos = atomicAdd(&ctrl[16 + e], 1);
    row_tok[pos] = t;
    row_w[pos] = t_w[t * 2 + s];
    inv_row[t * 2 + s] = pos;
  }
}

// ---------------- GEMM1: G = silu(X@W1) * (X@W2) * row_weight ----------------
// block 256 thr (4 waves, 2x2 of 64x64), tile 128(M) x 128(N=H), BK=32
__global__ __launch_bounds__(256) void gemm1_kernel(
    const unsigned short* __restrict__ xbf,   // [T][D]
    const unsigned short* __restrict__ w1t,   // [E][H][D]
    const unsigned short* __restrict__ w2t,   // [E][H][D]
    const int* __restrict__ row_tok, const float* __restrict__ row_w,
    const int* __restrict__ ctrl, unsigned short* __restrict__ G) {
  int e = blockIdx.z, mt = blockIdx.y, nt = blockIdx.x;
  int cnt = ctrl[e];
  if (mt * 128 >= cnt) return;
  int off = ctrl[8 + e];

  __shared__ unsigned short Asm[128 * 32];
  __shared__ unsigned short B1sm[128 * 32];
  __shared__ unsigned short B2sm[128 * 32];

  int tid = threadIdx.x, lane = tid & 63;
  const unsigned short* w1e = w1t + (size_t)e * (HDIM * DDIM);
  const unsigned short* w2e = w2t + (size_t)e * (HDIM * DDIM);

  int c = tid & 3;                       // 16B chunk in a 64B row
  int r0 = tid >> 2, r1 = (tid + 256) >> 2;
  int tok0 = row_tok[off + imin(mt * 128 + r0, cnt - 1)];
  int tok1 = row_tok[off + imin(mt * 128 + r1, cnt - 1)];
  const unsigned short* a0 = xbf + (size_t)tok0 * DDIM + c * 8;
  const unsigned short* a1 = xbf + (size_t)tok1 * DDIM + c * 8;
  const unsigned short* b10 = w1e + (size_t)(nt * 128 + r0) * DDIM + c * 8;
  const unsigned short* b11 = w1e + (size_t)(nt * 128 + r1) * DDIM + c * 8;
  const unsigned short* b20 = w2e + (size_t)(nt * 128 + r0) * DDIM + c * 8;
  const unsigned short* b21 = w2e + (size_t)(nt * 128 + r1) * DDIM + c * 8;

  f32x4 z = {0.f, 0.f, 0.f, 0.f};
  f32x4 acc1[4][4], acc2[4][4];
  #pragma unroll
  for (int m = 0; m < 4; ++m)
    #pragma unroll
    for (int n = 0; n < 4; ++n) { acc1[m][n] = z; acc2[m][n] = z; }

  int wr = (tid >> 7) & 1, wc = (tid >> 6) & 1;
  int lr = lane & 15, kr = (lane >> 4) * 8;
  const unsigned short* Af = Asm + (wr * 64 + lr) * 32 + kr;
  const unsigned short* B1f = B1sm + (wc * 64 + lr) * 32 + kr;
  const unsigned short* B2f = B2sm + (wc * 64 + lr) * 32 + kr;

  for (int k0 = 0; k0 < DDIM; k0 += 32) {
    gload16(a0 + k0, Asm + tid * 8);
    gload16(a1 + k0, Asm + (tid + 256) * 8);
    gload16(b10 + k0, B1sm + tid * 8);
    gload16(b11 + k0, B1sm + (tid + 256) * 8);
    gload16(b20 + k0, B2sm + tid * 8);
    gload16(b21 + k0, B2sm + (tid + 256) * 8);
    __syncthreads();
    short8 af[4], b1[4], b2[4];
    #pragma unroll
    for (int m = 0; m < 4; ++m) af[m] = *(const short8*)(Af + m * 16 * 32);
    #pragma unroll
    for (int n = 0; n < 4; ++n) b1[n] = *(const short8*)(B1f + n * 16 * 32);
    #pragma unroll
    for (int n = 0; n < 4; ++n) b2[n] = *(const short8*)(B2f + n * 16 * 32);
    #pragma unroll
    for (int m = 0; m < 4; ++m)
      #pragma unroll
      for (int n = 0; n < 4; ++n) {
        acc1[m][n] = __builtin_amdgcn_mfma_f32_16x16x32_bf16(af[m], b1[n], acc1[m][n], 0, 0, 0);
        acc2[m][n] = __builtin_amdgcn_mfma_f32_16x16x32_bf16(af[m], b2[n], acc2[m][n], 0, 0, 0);
      }
    __syncthreads();
  }

  int rbase = mt * 128 + wr * 64;
  float wrow[4][4];
  #pragma unroll
  for (int m = 0; m < 4; ++m)
    #pragma unroll
    for (int j = 0; j < 4; ++j) {
      int rl = rbase + m * 16 + (lane >> 4) * 4 + j;
      wrow[m][j] = (rl < cnt) ? row_w[off + rl] : 0.f;
    }
  #pragma unroll
  for (int m = 0; m < 4; ++m)
    #pragma unroll
    for (int j = 0; j < 4; ++j) {
      int rl = rbase + m * 16 + (lane >> 4) * 4 + j;
      if (rl < cnt) {
        size_t grow = (size_t)(off + rl) * HDIM + nt * 128 + wc * 64 + (lane & 15);
        #pragma unroll
        for (int n = 0; n < 4; ++n) {
          float h1 = acc1[m][n][j];
          float h2 = acc2[m][n][j];
          float g = (h1 / (1.f + __expf(-h1))) * h2 * wrow[m][j];
          G[grow + n * 16] = f2bf(g);
        }
      }
    }
}

// ---------------- GEMM2: Y = G @ W3 ----------------
__global__ __launch_bounds__(256) void gemm2_kernel(
    const unsigned short* __restrict__ G,     // [16384][H]
    const unsigned short* __restrict__ w3t,   // [E][D][H]
    const int* __restrict__ ctrl, unsigned short* __restrict__ Y) {
  int e = blockIdx.z, mt = blockIdx.y, nt = blockIdx.x;  // nt over D/128
  int cnt = ctrl[e];
  if (mt * 128 >= cnt) return;
  int off = ctrl[8 + e];

  __shared__ unsigned short Asm[128 * 32];
  __shared__ unsigned short Bsm[128 * 32];

  int tid = threadIdx.x, lane = tid & 63;
  const unsigned short* w3e = w3t + (size_t)e * (DDIM * HDIM);
  int c = tid & 3;
  int r0 = tid >> 2, r1 = (tid + 256) >> 2;
  const unsigned short* a0 = G + (size_t)(off + imin(mt * 128 + r0, cnt - 1)) * HDIM + c * 8;
  const unsigned short* a1 = G + (size_t)(off + imin(mt * 128 + r1, cnt - 1)) * HDIM + c * 8;
  const unsigned short* b0 = w3e + (size_t)(nt * 128 + r0) * HDIM + c * 8;
  const unsigned short* b1 = w3e + (size_t)(nt * 128 + r1) * HDIM + c * 8;

  f32x4 z = {0.f, 0.f, 0.f, 0.f};
  f32x4 acc[4][4];
  #pragma unroll
  for (int m = 0; m < 4; ++m)
    #pragma unroll
    for (int n = 0; n < 4; ++n) acc[m][n] = z;

  int wr = (tid >> 7) & 1, wc = (tid >> 6) & 1;
  int lr = lane & 15, kr = (lane >> 4) * 8;
  const unsigned short* Af = Asm + (wr * 64 + lr) * 32 + kr;
  const unsigned short* Bf = Bsm + (wc * 64 + lr) * 32 + kr;

  for (int k0 = 0; k0 < HDIM; k0 += 32) {
    gload16(a0 + k0, Asm + tid * 8);
    gload16(a1 + k0, Asm + (tid + 256) * 8);
    gload16(b0 + k0, Bsm + tid * 8);
    gload16(b1 + k0, Bsm + (tid + 256) * 8);
    __syncthreads();
    short8 af[4], bf[4];
    #pragma unroll
    for (int m = 0; m < 4; ++m) af[m] = *(const short8*)(Af + m * 16 * 32);
    #pragma unroll
    for (int n = 0; n < 4; ++n) bf[n] = *(const short8*)(Bf + n * 16 * 32);
    #pragma unroll
    for (int m = 0; m < 4; ++m)
      #pragma unroll
      for (int n = 0; n < 4; ++n)
        acc[m][n] = __builtin_amdgcn_mfma_f32_16x16x32_bf16(af[m], bf[n], acc[m][n], 0, 0, 0);
    __syncthreads();
  }

  #pragma unroll
  for (int m = 0; m < 4; ++m)
    #pragma unroll
    for (int j = 0; j < 4; ++j) {
      int rl = mt * 128 + wr * 64 + m * 16 + (lane >> 4) * 4 + j;
      if (rl < cnt) {
        size_t yrow = (size_t)(off + rl) * DDIM + nt * 128 + wc * 64 + (lane & 15);
        #pragma unroll
        for (int n = 0; n < 4; ++n) Y[yrow + n * 16] = f2bf(acc[m][n][j]);
      }
    }
}

// ---------------- combine: out[t] = Y[rowA] + Y[rowB] ----------------
__global__ __launch_bounds__(256) void combine_kernel(const unsigned short* __restrict__ Y,
                                                      const int* __restrict__ inv_row,
                                                      float* __restrict__ out) {
  int gid = blockIdx.x * 256 + threadIdx.x;   // 8192 * 128
  int t = gid >> 7;
  int cidx = (gid & 127) * 8;
  int rA = inv_row[t * 2], rB = inv_row[t * 2 + 1];
  uint4 va = *(const uint4*)(Y + (size_t)rA * DDIM + cidx);
  uint4 vb = *(const uint4*)(Y + (size_t)rB * DDIM + cidx);
  const unsigned short* pa = (const unsigned short*)&va;
  const unsigned short* pb = (const unsigned short*)&vb;
  float4 o0, o1;
  o0.x = bf2f(pa[0]) + bf2f(pb[0]); o0.y = bf2f(pa[1]) + bf2f(pb[1]);
  o0.z = bf2f(pa[2]) + bf2f(pb[2]); o0.w = bf2f(pa[3]) + bf2f(pb[3]);
  o1.x = bf2f(pa[4]) + bf2f(pb[4]); o1.y = bf2f(pa[5]) + bf2f(pb[5]);
  o1.z = bf2f(pa[6]) + bf2f(pb[6]); o1.w = bf2f(pa[7]) + bf2f(pb[7]);
  float* op = out + (size_t)t * DDIM + cidx;
  *(float4*)op = o0;
  *(float4*)(op + 4) = o1;
}

extern "C" void kernel_launch(void* const* d_in, const int* in_sizes, int n_in,
                              void* d_out, int out_size, void* d_ws, size_t ws_size,
                              hipStream_t stream) {
  const float* x  = (const float*)d_in[0];
  const float* gw = (const float*)d_in[1];
  const float* w1 = (const float*)d_in[2];
  const float* w2 = (const float*)d_in[3];
  const float* w3 = (const float*)d_in[4];
  float* out = (float*)d_out;
  char* ws = (char*)d_ws;

  // workspace layout (bytes); total ~218.4 MB
  unsigned short* xbf = (unsigned short*)(ws + 0);             // 16,777,216
  unsigned short* w1t = (unsigned short*)(ws + 16777216);      // 33,554,432
  unsigned short* w2t = (unsigned short*)(ws + 50331648);      // 33,554,432
  unsigned short* w3t = (unsigned short*)(ws + 83886080);      // 33,554,432
  unsigned short* G   = (unsigned short*)(ws + 117440512);     // 67,108,864
  unsigned short* Y   = (unsigned short*)(ws + 184549376);     // 33,554,432
  int*   row_tok = (int*)  (ws + 218103808);                   // 65,536
  float* row_w   = (float*)(ws + 218169344);                   // 65,536
  int*   inv_row = (int*)  (ws + 218234880);                   // 65,536
  int*   t_exp   = (int*)  (ws + 218300416);                   // 65,536
  float* t_w     = (float*)(ws + 218365952);                   // 65,536
  int*   ctrl    = (int*)  (ws + 218431488);                   // 96

  hipMemsetAsync(ctrl, 0, 96, stream);

  cvt_kernel<<<4096, 256, 0, stream>>>(x, xbf, T_TOK * DDIM);
  tcvt_kernel<<<dim3(32, 16, 8), 256, 0, stream>>>(w1, w1t, DDIM, HDIM);  // [D][H]->[H][D]
  tcvt_kernel<<<dim3(32, 16, 8), 256, 0, stream>>>(w2, w2t, DDIM, HDIM);
  tcvt_kernel<<<dim3(16, 32, 8), 256, 0, stream>>>(w3, w3t, HDIM, DDIM);  // [H][D]->[D][H]

  gate_kernel<<<2048, 256, 0, stream>>>(x, gw, t_exp, t_w, ctrl);
  offsets_kernel<<<1, 64, 0, stream>>>(ctrl);
  scatter_kernel<<<32, 256, 0, stream>>>(t_exp, t_w, ctrl, row_tok, row_w, inv_row);

  gemm1_kernel<<<dim3(16, 64, 8), 256, 0, stream>>>(xbf, w1t, w2t, row_tok, row_w, ctrl, G);
  gemm2_kernel<<<dim3(8, 64, 8), 256, 0, stream>>>(G, w3t, ctrl, Y);
  combine_kernel<<<4096, 256, 0, stream>>>(Y, inv_row, out);
}

// Round 3
// 812.307 us; speedup vs baseline: 1.0155x; 1.0155x over previous
//
#include <hip/hip_runtime.h>

#define T_TOK 8192
#define DDIM 1024
#define HDIM 2048
#define NEXP 8

typedef __attribute__((ext_vector_type(8))) short short8;
typedef __attribute__((ext_vector_type(4))) float f32x4;

__device__ __forceinline__ unsigned short f2bf(float f) {
  unsigned int u = __builtin_bit_cast(unsigned int, f);
  u += 0x7fffu + ((u >> 16) & 1u);   // RNE
  return (unsigned short)(u >> 16);
}
__device__ __forceinline__ float bf2f(unsigned short h) {
  unsigned int u = ((unsigned int)h) << 16;
  return __builtin_bit_cast(float, u);
}
__device__ __forceinline__ void gload16(const void* g, void* l) {
  __builtin_amdgcn_global_load_lds((const __attribute__((address_space(1))) void*)g,
                                   (__attribute__((address_space(3))) void*)l, 16, 0, 0);
}
__device__ __forceinline__ int imin(int a, int b) { return a < b ? a : b; }

// ---------------- fp32 -> bf16 straight convert (x) ----------------
__global__ __launch_bounds__(256) void cvt_kernel(const float* __restrict__ in,
                                                  unsigned short* __restrict__ out, int n) {
  int i = (blockIdx.x * 256 + threadIdx.x) * 8;
  int stride = gridDim.x * 256 * 8;
  for (; i < n; i += stride) {
    float4 a = *(const float4*)(in + i);
    float4 b = *(const float4*)(in + i + 4);
    alignas(16) unsigned short t[8] = {f2bf(a.x), f2bf(a.y), f2bf(a.z), f2bf(a.w),
                                       f2bf(b.x), f2bf(b.y), f2bf(b.z), f2bf(b.w)};
    *(uint4*)(out + i) = *(const uint4*)t;
  }
}

// ------------- fp32 [E][R][C] -> bf16 [E][C][R] transpose-convert -------------
__global__ __launch_bounds__(256) void tcvt_kernel(const float* __restrict__ in,
                                                   unsigned short* __restrict__ out,
                                                   int R, int C) {
  int e = blockIdx.z;
  int rb = blockIdx.y * 64, cb = blockIdx.x * 64;
  const float* inE = in + (size_t)e * R * C;
  unsigned short* outE = out + (size_t)e * R * C;
  __shared__ float tile[64][65];
  int tid = threadIdx.x;
  #pragma unroll
  for (int i = 0; i < 4; ++i) {
    int f = tid + i * 256;
    int r = f >> 4, c4 = (f & 15) << 2;
    float4 v = *(const float4*)(inE + (size_t)(rb + r) * C + cb + c4);
    tile[r][c4] = v.x; tile[r][c4 + 1] = v.y; tile[r][c4 + 2] = v.z; tile[r][c4 + 3] = v.w;
  }
  __syncthreads();
  #pragma unroll
  for (int i = 0; i < 2; ++i) {
    int g = tid + i * 256;
    int oc = g >> 3;          // original col = out row (0..63)
    int r8 = (g & 7) << 3;    // original row block (0..56)
    alignas(16) unsigned short tmp[8];
    #pragma unroll
    for (int j = 0; j < 8; ++j) tmp[j] = f2bf(tile[r8 + j][oc]);
    *(uint4*)(outE + (size_t)(cb + oc) * R + rb + r8) = *(const uint4*)tmp;
  }
}

// ---------------- gating: logits, softmax, top-2, counts ----------------
__global__ __launch_bounds__(256) void gate_kernel(const float* __restrict__ x,
                                                   const float* __restrict__ gw,
                                                   int* __restrict__ t_exp,
                                                   float* __restrict__ t_w,
                                                   int* __restrict__ counts) {
  int t = blockIdx.x * 4 + (threadIdx.x >> 6);
  int lane = threadIdx.x & 63;
  const float* xp = x + (size_t)t * DDIM;
  float acc[NEXP];
  #pragma unroll
  for (int e = 0; e < NEXP; ++e) acc[e] = 0.f;
  for (int i = 0; i < DDIM / 64; ++i) {
    int d = i * 64 + lane;
    float xv = xp[d];
    const float* g = gw + d * NEXP;
    #pragma unroll
    for (int e = 0; e < NEXP; ++e) acc[e] += xv * g[e];
  }
  #pragma unroll
  for (int off = 32; off > 0; off >>= 1) {
    #pragma unroll
    for (int e = 0; e < NEXP; ++e) acc[e] += __shfl_xor(acc[e], off, 64);
  }
  float mx = acc[0];
  #pragma unroll
  for (int e = 1; e < NEXP; ++e) mx = fmaxf(mx, acc[e]);
  float p[NEXP]; float S = 0.f;
  #pragma unroll
  for (int e = 0; e < NEXP; ++e) { p[e] = expf(acc[e] - mx); S += p[e]; }
  int i0 = 0; float v0 = p[0];
  #pragma unroll
  for (int e = 1; e < NEXP; ++e) if (p[e] > v0) { v0 = p[e]; i0 = e; }
  int i1 = -1; float v1 = -1.f;
  #pragma unroll
  for (int e = 0; e < NEXP; ++e) if (e != i0 && p[e] > v1) { v1 = p[e]; i1 = e; }
  float pv0 = v0 / S, pv1 = v1 / S;
  float denom = pv0 + pv1 + 1e-9f;
  if (lane == 0) {
    t_exp[t * 2] = i0; t_exp[t * 2 + 1] = i1;
    t_w[t * 2] = pv0 / denom; t_w[t * 2 + 1] = pv1 / denom;
    atomicAdd(&counts[i0], 1); atomicAdd(&counts[i1], 1);
  }
}

// ctrl layout: [0..8) counts, [8..16) offsets, [16..24) cursors
__global__ void offsets_kernel(int* ctrl) {
  if (threadIdx.x == 0 && blockIdx.x == 0) {
    int o = 0;
    for (int e = 0; e < NEXP; ++e) { ctrl[8 + e] = o; ctrl[16 + e] = o; o += ctrl[e]; }
  }
}

__global__ __launch_bounds__(256) void scatter_kernel(const int* __restrict__ t_exp,
                                                      const float* __restrict__ t_w,
                                                      int* __restrict__ ctrl,
                                                      int* __restrict__ row_tok,
                                                      float* __restrict__ row_w,
                                                      int* __restrict__ inv_row) {
  int t = blockIdx.x * 256 + threadIdx.x;
  if (t >= T_TOK) return;
  for (int s = 0; s < 2; ++s) {
    int e = t_exp[t * 2 + s];
    int pos = atomicAdd(&ctrl[16 + e], 1);
    row_tok[pos] = t;
    row_w[pos] = t_w[t * 2 + s];
    inv_row[t * 2 + s] = pos;
  }
}

// ---------------- GEMM1: G = silu(X@W1) * (X@W2) * row_weight ----------------
// 2-phase double-buffered pipeline, bank-conflict XOR swizzle, XCD-chunked grid.
// block 256 thr (4 waves, 2x2 of 64x64), tile 128(M) x 128(N=H), BK=32
__global__ __launch_bounds__(256) void gemm1_kernel(
    const unsigned short* __restrict__ xbf,   // [T][D]
    const unsigned short* __restrict__ w1t,   // [E][H][D]
    const unsigned short* __restrict__ w2t,   // [E][H][D]
    const int* __restrict__ row_tok, const float* __restrict__ row_w,
    const int* __restrict__ ctrl, unsigned short* __restrict__ G) {
  // flattened grid 8192 = 8 e * 16 nt * 64 mt (mt fastest); XCD-chunked swizzle
  int bid = blockIdx.x;
  int idx = (bid & 7) * 1024 + (bid >> 3);
  int mt = idx & 63, nt = (idx >> 6) & 15, e = idx >> 10;
  int cnt = ctrl[e];
  if (mt * 128 >= cnt) return;
  int off = ctrl[8 + e];

  __shared__ unsigned short Asm[2][128 * 32];
  __shared__ unsigned short B1sm[2][128 * 32];
  __shared__ unsigned short B2sm[2][128 * 32];

  int tid = threadIdx.x, lane = tid & 63;
  const unsigned short* w1e = w1t + (size_t)e * (HDIM * DDIM);
  const unsigned short* w2e = w2t + (size_t)e * (HDIM * DDIM);

  // staging: thread (r0 = tid>>2, c = tid&3) -> LDS linear slot tid*16B.
  // source chunk pre-swizzled: cs = c ^ ((r0>>1)&3)  (same for r0 and r0+64)
  int c = tid & 3;
  int r0 = tid >> 2, r1 = r0 + 64;
  int cs8 = (c ^ ((r0 >> 1) & 3)) * 8;
  int tok0 = row_tok[off + imin(mt * 128 + r0, cnt - 1)];
  int tok1 = row_tok[off + imin(mt * 128 + r1, cnt - 1)];
  const unsigned short* a0 = xbf + (size_t)tok0 * DDIM + cs8;
  const unsigned short* a1 = xbf + (size_t)tok1 * DDIM + cs8;
  const unsigned short* b10 = w1e + (size_t)(nt * 128 + r0) * DDIM + cs8;
  const unsigned short* b11 = w1e + (size_t)(nt * 128 + r1) * DDIM + cs8;
  const unsigned short* b20 = w2e + (size_t)(nt * 128 + r0) * DDIM + cs8;
  const unsigned short* b21 = w2e + (size_t)(nt * 128 + r1) * DDIM + cs8;

  f32x4 z = {0.f, 0.f, 0.f, 0.f};
  f32x4 acc1[4][4], acc2[4][4];
  #pragma unroll
  for (int m = 0; m < 4; ++m)
    #pragma unroll
    for (int n = 0; n < 4; ++n) { acc1[m][n] = z; acc2[m][n] = z; }

  int wr = (tid >> 7) & 1, wc = (tid >> 6) & 1;
  int lr = lane & 15;
  int v = (lr >> 1) & 3;                       // read-side swizzle key
  int koff = ((lane >> 4) ^ v) * 8;            // physical chunk for wanted k-slice
  int aoff = (wr * 64 + lr) * 32 + koff;
  int boff = (wc * 64 + lr) * 32 + koff;

#define G1_STAGE(B, KT) do { int _k = (KT) * 32;                         \
    gload16(a0 + _k, &Asm[B][0] + tid * 8);                              \
    gload16(a1 + _k, &Asm[B][0] + (tid + 256) * 8);                      \
    gload16(b10 + _k, &B1sm[B][0] + tid * 8);                            \
    gload16(b11 + _k, &B1sm[B][0] + (tid + 256) * 8);                    \
    gload16(b20 + _k, &B2sm[B][0] + tid * 8);                            \
    gload16(b21 + _k, &B2sm[B][0] + (tid + 256) * 8); } while (0)

#define G1_COMP(B) do {                                                  \
    short8 af[4], b1v[4], b2v[4];                                        \
    _Pragma("unroll")                                                    \
    for (int m = 0; m < 4; ++m) af[m] = *(const short8*)(&Asm[B][0] + aoff + m * 512); \
    _Pragma("unroll")                                                    \
    for (int n = 0; n < 4; ++n) b1v[n] = *(const short8*)(&B1sm[B][0] + boff + n * 512); \
    _Pragma("unroll")                                                    \
    for (int n = 0; n < 4; ++n) b2v[n] = *(const short8*)(&B2sm[B][0] + boff + n * 512); \
    __builtin_amdgcn_s_setprio(1);                                       \
    _Pragma("unroll")                                                    \
    for (int m = 0; m < 4; ++m)                                          \
      _Pragma("unroll")                                                  \
      for (int n = 0; n < 4; ++n) {                                      \
        acc1[m][n] = __builtin_amdgcn_mfma_f32_16x16x32_bf16(af[m], b1v[n], acc1[m][n], 0, 0, 0); \
        acc2[m][n] = __builtin_amdgcn_mfma_f32_16x16x32_bf16(af[m], b2v[n], acc2[m][n], 0, 0, 0); \
      }                                                                  \
    __builtin_amdgcn_s_setprio(0); } while (0)

  G1_STAGE(0, 0);
  #pragma unroll 1
  for (int kt = 0; kt < 32; kt += 2) {
    __syncthreads();                    // buf0 staged data ready
    G1_STAGE(1, kt + 1);                // overlap: next tile in flight
    G1_COMP(0);
    __syncthreads();                    // buf1 ready
    if (kt + 2 < 32) G1_STAGE(0, kt + 2);
    G1_COMP(1);
  }
#undef G1_STAGE
#undef G1_COMP

  int rbase = mt * 128 + wr * 64;
  #pragma unroll
  for (int m = 0; m < 4; ++m)
    #pragma unroll
    for (int j = 0; j < 4; ++j) {
      int rl = rbase + m * 16 + (lane >> 4) * 4 + j;
      if (rl < cnt) {
        float wrj = row_w[off + rl];
        size_t grow = (size_t)(off + rl) * HDIM + nt * 128 + wc * 64 + lr;
        #pragma unroll
        for (int n = 0; n < 4; ++n) {
          float h1 = acc1[m][n][j];
          float h2 = acc2[m][n][j];
          float g = (h1 / (1.f + __expf(-h1))) * h2 * wrj;
          G[grow + n * 16] = f2bf(g);
        }
      }
    }
}

// ---------------- GEMM2: Y = G @ W3 ----------------
__global__ __launch_bounds__(256) void gemm2_kernel(
    const unsigned short* __restrict__ G,     // [16384][H]
    const unsigned short* __restrict__ w3t,   // [E][D][H]
    const int* __restrict__ ctrl, unsigned short* __restrict__ Y) {
  // flattened grid 4096 = 8 e * 8 nt * 64 mt (mt fastest); XCD-chunked swizzle
  int bid = blockIdx.x;
  int idx = (bid & 7) * 512 + (bid >> 3);
  int mt = idx & 63, nt = (idx >> 6) & 7, e = idx >> 9;
  int cnt = ctrl[e];
  if (mt * 128 >= cnt) return;
  int off = ctrl[8 + e];

  __shared__ unsigned short Asm[2][128 * 32];
  __shared__ unsigned short Bsm[2][128 * 32];

  int tid = threadIdx.x, lane = tid & 63;
  const unsigned short* w3e = w3t + (size_t)e * (DDIM * HDIM);
  int c = tid & 3;
  int r0 = tid >> 2, r1 = r0 + 64;
  int cs8 = (c ^ ((r0 >> 1) & 3)) * 8;
  const unsigned short* a0 = G + (size_t)(off + imin(mt * 128 + r0, cnt - 1)) * HDIM + cs8;
  const unsigned short* a1 = G + (size_t)(off + imin(mt * 128 + r1, cnt - 1)) * HDIM + cs8;
  const unsigned short* b0 = w3e + (size_t)(nt * 128 + r0) * HDIM + cs8;
  const unsigned short* b1 = w3e + (size_t)(nt * 128 + r1) * HDIM + cs8;

  f32x4 z = {0.f, 0.f, 0.f, 0.f};
  f32x4 acc[4][4];
  #pragma unroll
  for (int m = 0; m < 4; ++m)
    #pragma unroll
    for (int n = 0; n < 4; ++n) acc[m][n] = z;

  int wr = (tid >> 7) & 1, wc = (tid >> 6) & 1;
  int lr = lane & 15;
  int v = (lr >> 1) & 3;
  int koff = ((lane >> 4) ^ v) * 8;
  int aoff = (wr * 64 + lr) * 32 + koff;
  int boff = (wc * 64 + lr) * 32 + koff;

#define G2_STAGE(B, KT) do { int _k = (KT) * 32;                         \
    gload16(a0 + _k, &Asm[B][0] + tid * 8);                              \
    gload16(a1 + _k, &Asm[B][0] + (tid + 256) * 8);                      \
    gload16(b0 + _k, &Bsm[B][0] + tid * 8);                              \
    gload16(b1 + _k, &Bsm[B][0] + (tid + 256) * 8); } while (0)

#define G2_COMP(B) do {                                                  \
    short8 af[4], bfv[4];                                                \
    _Pragma("unroll")                                                    \
    for (int m = 0; m < 4; ++m) af[m] = *(const short8*)(&Asm[B][0] + aoff + m * 512); \
    _Pragma("unroll")                                                    \
    for (int n = 0; n < 4; ++n) bfv[n] = *(const short8*)(&Bsm[B][0] + boff + n * 512); \
    __builtin_amdgcn_s_setprio(1);                                       \
    _Pragma("unroll")                                                    \
    for (int m = 0; m < 4; ++m)                                          \
      _Pragma("unroll")                                                  \
      for (int n = 0; n < 4; ++n)                                        \
        acc[m][n] = __builtin_amdgcn_mfma_f32_16x16x32_bf16(af[m], bfv[n], acc[m][n], 0, 0, 0); \
    __builtin_amdgcn_s_setprio(0); } while (0)

  G2_STAGE(0, 0);
  #pragma unroll 1
  for (int kt = 0; kt < 64; kt += 2) {
    __syncthreads();
    G2_STAGE(1, kt + 1);
    G2_COMP(0);
    __syncthreads();
    if (kt + 2 < 64) G2_STAGE(0, kt + 2);
    G2_COMP(1);
  }
#undef G2_STAGE
#undef G2_COMP

  #pragma unroll
  for (int m = 0; m < 4; ++m)
    #pragma unroll
    for (int j = 0; j < 4; ++j) {
      int rl = mt * 128 + wr * 64 + m * 16 + (lane >> 4) * 4 + j;
      if (rl < cnt) {
        size_t yrow = (size_t)(off + rl) * DDIM + nt * 128 + wc * 64 + lr;
        #pragma unroll
        for (int n = 0; n < 4; ++n) Y[yrow + n * 16] = f2bf(acc[m][n][j]);
      }
    }
}

// ---------------- combine: out[t] = Y[rowA] + Y[rowB] ----------------
__global__ __launch_bounds__(256) void combine_kernel(const unsigned short* __restrict__ Y,
                                                      const int* __restrict__ inv_row,
                                                      float* __restrict__ out) {
  int gid = blockIdx.x * 256 + threadIdx.x;   // 8192 * 128
  int t = gid >> 7;
  int cidx = (gid & 127) * 8;
  int rA = inv_row[t * 2], rB = inv_row[t * 2 + 1];
  uint4 va = *(const uint4*)(Y + (size_t)rA * DDIM + cidx);
  uint4 vb = *(const uint4*)(Y + (size_t)rB * DDIM + cidx);
  const unsigned short* pa = (const unsigned short*)&va;
  const unsigned short* pb = (const unsigned short*)&vb;
  float4 o0, o1;
  o0.x = bf2f(pa[0]) + bf2f(pb[0]); o0.y = bf2f(pa[1]) + bf2f(pb[1]);
  o0.z = bf2f(pa[2]) + bf2f(pb[2]); o0.w = bf2f(pa[3]) + bf2f(pb[3]);
  o1.x = bf2f(pa[4]) + bf2f(pb[4]); o1.y = bf2f(pa[5]) + bf2f(pb[5]);
  o1.z = bf2f(pa[6]) + bf2f(pb[6]); o1.w = bf2f(pa[7]) + bf2f(pb[7]);
  float* op = out + (size_t)t * DDIM + cidx;
  *(float4*)op = o0;
  *(float4*)(op + 4) = o1;
}

extern "C" void kernel_launch(void* const* d_in, const int* in_sizes, int n_in,
                              void* d_out, int out_size, void* d_ws, size_t ws_size,
                              hipStream_t stream) {
  const float* x  = (const float*)d_in[0];
  const float* gw = (const float*)d_in[1];
  const float* w1 = (const float*)d_in[2];
  const float* w2 = (const float*)d_in[3];
  const float* w3 = (const float*)d_in[4];
  float* out = (float*)d_out;
  char* ws = (char*)d_ws;

  // workspace layout (bytes); total ~218.4 MB
  unsigned short* xbf = (unsigned short*)(ws + 0);             // 16,777,216
  unsigned short* w1t = (unsigned short*)(ws + 16777216);      // 33,554,432
  unsigned short* w2t = (unsigned short*)(ws + 50331648);      // 33,554,432
  unsigned short* w3t = (unsigned short*)(ws + 83886080);      // 33,554,432
  unsigned short* G   = (unsigned short*)(ws + 117440512);     // 67,108,864
  unsigned short* Y   = (unsigned short*)(ws + 184549376);     // 33,554,432
  int*   row_tok = (int*)  (ws + 218103808);                   // 65,536
  float* row_w   = (float*)(ws + 218169344);                   // 65,536
  int*   inv_row = (int*)  (ws + 218234880);                   // 65,536
  int*   t_exp   = (int*)  (ws + 218300416);                   // 65,536
  float* t_w     = (float*)(ws + 218365952);                   // 65,536
  int*   ctrl    = (int*)  (ws + 218431488);                   // 96

  hipMemsetAsync(ctrl, 0, 96, stream);

  cvt_kernel<<<4096, 256, 0, stream>>>(x, xbf, T_TOK * DDIM);
  tcvt_kernel<<<dim3(32, 16, 8), 256, 0, stream>>>(w1, w1t, DDIM, HDIM);  // [D][H]->[H][D]
  tcvt_kernel<<<dim3(32, 16, 8), 256, 0, stream>>>(w2, w2t, DDIM, HDIM);
  tcvt_kernel<<<dim3(16, 32, 8), 256, 0, stream>>>(w3, w3t, HDIM, DDIM);  // [H][D]->[D][H]

  gate_kernel<<<2048, 256, 0, stream>>>(x, gw, t_exp, t_w, ctrl);
  offsets_kernel<<<1, 64, 0, stream>>>(ctrl);
  scatter_kernel<<<32, 256, 0, stream>>>(t_exp, t_w, ctrl, row_tok, row_w, inv_row);

  gemm1_kernel<<<8192, 256, 0, stream>>>(xbf, w1t, w2t, row_tok, row_w, ctrl, G);
  gemm2_kernel<<<4096, 256, 0, stream>>>(G, w3t, ctrl, Y);
  combine_kernel<<<4096, 256, 0, stream>>>(Y, inv_row, out);
}